// Round 14
// baseline (212.855 us; speedup 1.0000x reference)
//
#include <hip/hip_runtime.h>

// Problem constants (B=4, S=2048, D=1024, H=16, HD=64, theta=10000)
#define SB 2048
#define DM 1024
#define NH 16
#define HDim 64
#define NB 4
#define MROWS (NB*SB)   // 8192

typedef _Float16 h16;
typedef __attribute__((ext_vector_type(8))) _Float16 h16x8;
typedef __attribute__((ext_vector_type(4))) _Float16 h16x4;
typedef __attribute__((ext_vector_type(2))) _Float16 h16x2;
typedef __attribute__((ext_vector_type(2))) __fp16 fp16x2;
typedef __attribute__((ext_vector_type(4))) float f32x4;

typedef const __attribute__((address_space(1))) void* as1cp;
typedef __attribute__((address_space(3))) void* as3p;

__device__ __forceinline__ void gload16(const void* g, void* l){
  __builtin_amdgcn_global_load_lds((as1cp)g, (as3p)l, 16, 0, 0);
}
__device__ __forceinline__ int swz64(int a){ return a ^ (((a>>7)&3)<<4); }
__device__ __forceinline__ int swz128(int a){ return a ^ (((a>>7)&7)<<4); }
// V k-permutation (pos->k) inverse, used when writing VT (see round-1 notes)
__device__ __forceinline__ int invp3(int k){ return (k&32) | ((k&16)>>2) | ((k&12)<<1) | (k&3); }
__device__ __forceinline__ h16x2 pkrtz(float a, float b){
  fp16x2 r = __builtin_amdgcn_cvt_pkrtz(a,b);
  return __builtin_bit_cast(h16x2, r);
}

#define C1 0.18033688f   // 0.125 * log2(e); folded into wq at cvt_w

// ---------------- convert x (fp32 -> fp16) ----------------
__global__ void k_cvt_x(const float* __restrict__ x, h16* __restrict__ xb){
  const int n4 = MROWS*DM/4;
  for (int i = blockIdx.x*blockDim.x + threadIdx.x; i < n4; i += gridDim.x*blockDim.x){
    float4 v = ((const float4*)x)[i];
    h16x4 h; h[0]=(h16)v.x; h[1]=(h16)v.y; h[2]=(h16)v.z; h[3]=(h16)v.w;
    ((h16x4*)xb)[i] = h;
  }
}

// ---------------- RoPE cos/sin table: tab[s*32+pr] = {cos,sin} ----------------
__global__ void k_tab(const int* __restrict__ tok, float2* __restrict__ tab){
  int i = blockIdx.x*blockDim.x + threadIdx.x;   // 65536 entries
  int pr = i & 31, s = i >> 5;
  float inv = exp2f(-0.41524101f * (float)pr);
  float ang = (float)tok[s] * inv;
  float sn, cs; __sincosf(ang, &sn, &cs);
  tab[i] = make_float2(cs, sn);
}

// ------- transpose+convert weights: WT[z][n][k] = W_z[k][n]; wq pre-scaled by C1 -------
__global__ void k_cvt_w(const float* __restrict__ wq, const float* __restrict__ wk,
                        const float* __restrict__ wv, const float* __restrict__ wo,
                        h16* __restrict__ WT){
  const float* W = (blockIdx.z==0)?wq:(blockIdx.z==1)?wk:(blockIdx.z==2)?wv:wo;
  const float sc = (blockIdx.z==0) ? C1 : 1.0f;
  __shared__ h16 tile[32][33];
  int tx = threadIdx.x & 31, ty = threadIdx.x >> 5;
  int n0 = blockIdx.x*32, k0 = blockIdx.y*32;
  #pragma unroll
  for (int j=0;j<4;++j)
    tile[ty*4+j][tx] = (h16)(W[(size_t)(k0+ty*4+j)*DM + n0 + tx] * sc);
  __syncthreads();
  #pragma unroll
  for (int j=0;j<4;++j)
    WT[((size_t)blockIdx.z*DM + n0 + ty*4 + j)*DM + k0 + tx] = tile[tx][ty*4+j];
}

// -------- MFMA GEMM, 128x128 tile, BK=32, 4 waves, 2-phase LDS dbuf (R8-proven) --------
// XCD m-stripe partition (R13): XCD x owns m-panels [8x,8x+8); A stripe L2-resident.
// MODE 0: C=[8192]x[3072]; Q RoPE'd -> TRANSPOSED [bh][hd][s] (packed h16x4);
//         K RoPE'd -> [bh][s][hd] scatter; V -> permuted VT [bh][hd][pos].
// MODE 1: C=[8192]x[1024] -> fp32 linear to d_out
template<int MODE>
__global__ __launch_bounds__(256) void k_gemm(const h16* __restrict__ A,
                                              const h16* __restrict__ Bw,
                                              void* __restrict__ outp,
                                              const float2* __restrict__ tab){
  __shared__ __align__(16) char lds[32768];    // 2 x (As 8KB | Bs 8KB)
  const int t = threadIdx.x, lane = t & 63, wave = t >> 6;
  // XCD m-stripe block map (grid: MODE0=1536, MODE1=512; both %8==0)
  const int lin = blockIdx.x;
  const int x = lin & 7, local = lin >> 3;
  int m0p, n0p;
  if (MODE==0){ n0p = local % 24; m0p = local / 24; }
  else        { n0p = local & 7;  m0p = local >> 3; }
  const int m0 = (x*8 + m0p)*128, n0 = n0p*128;
  const int wm = (wave >> 1)*64, wn = (wave & 1)*64;
  // thread-constant staging offsets
  const int o0 = t*16, o1 = o0 + 4096;
  const int q0_ = swz64(o0), q1_ = swz64(o1);
  const int r0 = q0_ >> 6, c0 = q0_ & 63, r1 = q1_ >> 6, c1 = q1_ & 63;
  f32x4 acc[4][4] = {};
  { // prologue: stage tile 0 into buf 0
    gload16((const char*)A  + (size_t)(m0+r0)*2048 + c0, lds + o0);
    gload16((const char*)A  + (size_t)(m0+r1)*2048 + c1, lds + o1);
    gload16((const char*)Bw + (size_t)(n0+r0)*2048 + c0, lds + 8192 + o0);
    gload16((const char*)Bw + (size_t)(n0+r1)*2048 + c1, lds + 8192 + o1);
  }
  int cur = 0;
  for (int k0 = 0; k0 < DM; k0 += 32){
    __syncthreads();                       // vmcnt(0): buf[cur] staged; prev reads done
    if (k0 + 32 < DM){                     // stage next tile into buf[cur^1]
      const char* Ak = (const char*)A  + (k0+32)*2;
      const char* Bk = (const char*)Bw + (k0+32)*2;
      char* As1 = lds + (cur^1)*16384;
      gload16(Ak + (size_t)(m0+r0)*2048 + c0, As1 + o0);
      gload16(Ak + (size_t)(m0+r1)*2048 + c1, As1 + o1);
      gload16(Bk + (size_t)(n0+r0)*2048 + c0, As1 + 8192 + o0);
      gload16(Bk + (size_t)(n0+r1)*2048 + c1, As1 + 8192 + o1);
    }
    const char* As = lds + cur*16384;
    const char* Bs = As + 8192;
    h16x8 af[4], bf[4];
    #pragma unroll
    for (int f=0; f<4; ++f){
      int ao = (wm + f*16 + (lane&15))*64 + 16*(lane>>4);
      af[f] = *(const h16x8*)(As + swz64(ao));
      int bo = (wn + f*16 + (lane&15))*64 + 16*(lane>>4);
      bf[f] = *(const h16x8*)(Bs + swz64(bo));
    }
    __builtin_amdgcn_s_setprio(1);
    #pragma unroll
    for (int fm=0; fm<4; ++fm)
      #pragma unroll
      for (int fn=0; fn<4; ++fn)
        acc[fm][fn] = __builtin_amdgcn_mfma_f32_16x16x32_f16(af[fm], bf[fn], acc[fm][fn], 0,0,0);
    __builtin_amdgcn_s_setprio(0);
    cur ^= 1;
  }
  // epilogue; D layout: col = lane&15, row = 4*(lane>>4)+r
  #pragma unroll
  for (int fm=0; fm<4; ++fm){
    int grow0 = m0 + wm + fm*16 + 4*(lane>>4);
    #pragma unroll
    for (int fn=0; fn<4; ++fn){
      int gcol = n0 + wn + fn*16 + (lane&15);
      if (MODE == 0){
        int mat = gcol >> 10;                 // wave-uniform per fn
        int hh = (gcol >> 6) & 15, d = gcol & 63;
        if (mat == 0){
          // Q: RoPE then TRANSPOSED store [bh][d][s], packed h16x4 (s-contiguous)
          const int pr = d >> 1;
          int s0 = grow0 & 2047, b2 = grow0 >> 11;
          int bh = b2*16 + hh;
          float rs4[4];
          #pragma unroll
          for (int r=0;r<4;++r){
            float2 t2 = tab[(s0+r)*32 + pr];
            float val = acc[fm][fn][r];
            float oth = __shfl_xor(val, 1);
            rs4[r] = fmaf(val, t2.x, (d & 1) ? oth*t2.y : -(oth*t2.y));
          }
          union { h16x4 v4; h16x2 h2[2]; } u;
          u.h2[0] = pkrtz(rs4[0], rs4[1]);
          u.h2[1] = pkrtz(rs4[2], rs4[3]);
          *(h16x4*)((h16*)outp + (size_t)bh*131072 + (size_t)d*2048 + s0) = u.v4;
        } else if (mat == 1){
          // K: RoPE then [64+bh][s][hd] scatter (attn stages K rows by s)
          const int pr = d >> 1;
          #pragma unroll
          for (int r=0;r<4;++r){
            int grow = grow0 + r;
            int s = grow & 2047, b2 = grow >> 11;
            float2 t2 = tab[s*32 + pr];
            float val = acc[fm][fn][r];
            float oth = __shfl_xor(val, 1);
            float res = fmaf(val, t2.x, (d & 1) ? oth*t2.y : -(oth*t2.y));
            ((h16*)outp)[((size_t)(64 + b2*16 + hh)*SB + s)*HDim + d] = (h16)res;
          }
        } else {
          // VT scatter: pos runs consecutively with r -> one h16x4 store
          int s0 = grow0 & 2047, b2 = grow0 >> 11;
          int bh = b2*16 + hh;
          int pos0 = (s0 & ~63) + invp3(s0 & 63);
          union { h16x4 v4; h16x2 h2[2]; } u;
          u.h2[0] = pkrtz(acc[fm][fn][0], acc[fm][fn][1]);
          u.h2[1] = pkrtz(acc[fm][fn][2], acc[fm][fn][3]);
          *(h16x4*)((h16*)outp + (size_t)(128 + bh)*131072 + (size_t)d*2048 + pos0) = u.v4;
        }
      } else {
        #pragma unroll
        for (int r=0;r<4;++r){
          int grow = grow0 + r;
          ((float*)outp)[(size_t)grow*DM + gcol] = acc[fm][fn][r];
        }
      }
    }
  }
}

// ------- causal flash attention: 4 waves x 32q, paired-static, dbuf (R7 core + R8 balance) -------
// 512 blocks x 256 thr. Block = (bh, pair p): 128-row q-tiles J=15-p then J=p
// -> 34 k-tiles/block, perfect balance; 4 blocks/CU co-resident (vs 2 at 8-wave).
// Wave owns 32 q-rows (c=2 x 16). KVBLK=64 dbuf staging (2 K + 2 V gload16/thread).
// QK^T: mfma(K,Q) -> lane owns q-row, 16 keys in-reg. P = exp2(s) directly
// (Q pre-scaled by C1). Row-sum via mfma(ones,P). PV: mfma(VT,P), VT permuted.
// Q gathered from transposed [bh][hd][s] layout once per segment.
__global__ __launch_bounds__(256, 4) void k_attn(const h16* __restrict__ Qh,
                                                 const h16* __restrict__ Kh,
                                                 const h16* __restrict__ VTh,
                                                 h16* __restrict__ Ctx){
  __shared__ __align__(16) char Kl[2][8192];   // [64 k][64 hd], swz128
  __shared__ __align__(16) char Vl[2][8192];   // [64 hd][64 pos], swz128
  const int t = threadIdx.x, lane = t & 63, wave = t >> 6;
  const int g = lane >> 4, l15 = lane & 15;
  // lane-constant LDS read bases (see R4 notes): addr = kb_hs + 2048*u
  const int msk = (l15 & 7) << 4;
  const int kb0 = ((l15 << 7) + (g << 4)) ^ msk;
  const int kb1 = kb0 ^ 64;
  // thread-constant staging offsets (256 threads x 2 cover 8KB at 16B each)
  const int o0 = t*16, o1 = o0 + 4096;
  const int lo0 = swz128(o0), lo1 = swz128(o1);
  const int vof0 = ((lo0 >> 7) << 12) + (lo0 & 127);
  const int vof1 = ((lo1 >> 7) << 12) + (lo1 & 127);
  h16x8 ones;
  #pragma unroll
  for (int i=0;i<8;++i) ones[i] = (h16)1.0f;

  // static XCD-clustered item map: bh's 8 pair-blocks share blockIdx%8 -> one XCD
  const int lin = blockIdx.x;
  const int sz = (lin & 7)*64 + (lin >> 3);
  const int bh = sz >> 3, pr = sz & 7;
  const char* Qb = (const char*)Qh + (size_t)bh*262144;   // [64 hd][2048 s]
  const char* Kb = (const char*)Kh + (size_t)bh*262144;
  const char* Vb = (const char*)VTh + (size_t)bh*262144;  // [64 hd][2048 pos]
  const int b = bh >> 4, h = bh & 15;

  #pragma unroll
  for (int seg=0; seg<2; ++seg){
    const int J = seg ? pr : (15 - pr);    // heavy tile first
    const int qw = (J << 7) + wave*32;     // wave owns q in [qw, qw+32)
    // gather Q fragments from transposed layout: q = qw+16c+l15, hd = 8g+j (+32)
    h16x8 qf[2][2];
    #pragma unroll
    for (int c=0;c<2;++c){
      union { h16x8 v; h16 e[8]; } uq0, uq1;
      const char* Qcol = Qb + (size_t)(qw + 16*c + l15)*2;
      #pragma unroll
      for (int j=0;j<8;++j){
        uq0.e[j] = *(const h16*)(Qcol + (size_t)(8*g + j)*4096);
        uq1.e[j] = *(const h16*)(Qcol + (size_t)(32 + 8*g + j)*4096);
      }
      qf[c][0] = uq0.v; qf[c][1] = uq1.v;
    }
    f32x4 acc[2][4] = {};
    float lrow[2] = {0.f, 0.f};
    const int nkt = 2*J + 2;
    const char* kS0 = Kb + lo0;  const char* kS1 = Kb + lo1;
    const char* vS0 = Vb + vof0; const char* vS1 = Vb + vof1;
    __syncthreads();                       // prior seg's LDS reads done
    gload16(kS0, &Kl[0][o0]); gload16(kS1, &Kl[0][o1]);
    gload16(vS0, &Vl[0][o0]); gload16(vS1, &Vl[0][o1]);
    int buf = 0;
    for (int kt=0; kt<nkt; ++kt){
      __syncthreads();                     // drains vmcnt, publishes buf
      if (kt+1 < nkt){
        kS0 += 8192; kS1 += 8192; vS0 += 128; vS1 += 128;
        gload16(kS0, &Kl[buf^1][o0]); gload16(kS1, &Kl[buf^1][o1]);
        gload16(vS0, &Vl[buf^1][o0]); gload16(vS1, &Vl[buf^1][o1]);
      }
      const int k0 = kt << 6;
      if (k0 <= qw + 31){                  // wave-uniform causal skip
        const char* Kt = Kl[buf];
        const char* Vt = Vl[buf];
        f32x4 sfr[2][4] = {};
        #pragma unroll
        for (int hs=0;hs<2;++hs){
          h16x8 kfr[4];
          const int base = hs ? kb1 : kb0;
          #pragma unroll
          for (int kf=0;kf<4;++kf) kfr[kf] = *(const h16x8*)(Kt + base + 2048*kf);
          __builtin_amdgcn_s_setprio(1);
          #pragma unroll
          for (int c=0;c<2;++c)
            #pragma unroll
            for (int kf=0;kf<4;++kf)
              sfr[c][kf] = __builtin_amdgcn_mfma_f32_16x16x32_f16(kfr[kf], qf[c][hs], sfr[c][kf], 0,0,0);
          __builtin_amdgcn_s_setprio(0);
        }
        const bool diag = (k0 + 63 > qw);
        h16x8 pa[2][2];
        #pragma unroll
        for (int c=0;c<2;++c){
          if (diag){
            const int qg = qw + 16*c + l15;
            #pragma unroll
            for (int kf=0;kf<4;++kf){
              const int kb = k0 + 16*kf + 4*g;
              #pragma unroll
              for (int r=0;r<4;++r)
                if (kb + r > qg) sfr[c][kf][r] = -1e30f;
            }
          }
          float e[4][4];
          #pragma unroll
          for (int kf=0;kf<4;++kf)
            #pragma unroll
            for (int r=0;r<4;++r)
              e[kf][r] = exp2f(sfr[c][kf][r]);
          #pragma unroll
          for (int s=0;s<2;++s){
            union { h16x8 v8; h16x2 h2[4]; } u;
            u.h2[0] = pkrtz(e[2*s][0],   e[2*s][1]);
            u.h2[1] = pkrtz(e[2*s][2],   e[2*s][3]);
            u.h2[2] = pkrtz(e[2*s+1][0], e[2*s+1][1]);
            u.h2[3] = pkrtz(e[2*s+1][2], e[2*s+1][3]);
            pa[c][s] = u.v8;
          }
          f32x4 zs = {};
          zs = __builtin_amdgcn_mfma_f32_16x16x32_f16(ones, pa[c][0], zs, 0,0,0);
          zs = __builtin_amdgcn_mfma_f32_16x16x32_f16(ones, pa[c][1], zs, 0,0,0);
          lrow[c] += zs[0];
        }
        #pragma unroll
        for (int s=0;s<2;++s){
          h16x8 vb2[4];
          const int base = s ? kb1 : kb0;
          #pragma unroll
          for (int v=0;v<4;++v) vb2[v] = *(const h16x8*)(Vt + base + 2048*v);
          __builtin_amdgcn_s_setprio(1);
          #pragma unroll
          for (int c=0;c<2;++c)
            #pragma unroll
            for (int v=0;v<4;++v)
              acc[c][v] = __builtin_amdgcn_mfma_f32_16x16x32_f16(vb2[v], pa[c][s], acc[c][v], 0,0,0);
          __builtin_amdgcn_s_setprio(0);
        }
      }
      buf ^= 1;
    }
    // epilogue: lane owns row q = qw+16c+l15; cols hd = 16v+4g+r -> packed 8B stores
    #pragma unroll
    for (int c=0;c<2;++c){
      const float rinv = 1.0f / lrow[c];
      h16* basep = Ctx + ((size_t)(b*SB + qw + 16*c + l15))*DM + h*64 + (g<<2);
      #pragma unroll
      for (int v=0;v<4;++v){
        union { h16x4 v4; h16x2 h2[2]; } u;
        u.h2[0] = pkrtz(acc[c][v][0]*rinv, acc[c][v][1]*rinv);
        u.h2[1] = pkrtz(acc[c][v][2]*rinv, acc[c][v][3]*rinv);
        *(h16x4*)(basep + 16*v) = u.v4;
      }
    }
  }
}

extern "C" void kernel_launch(void* const* d_in, const int* in_sizes, int n_in,
                              void* d_out, int out_size, void* d_ws, size_t ws_size,
                              hipStream_t stream) {
  const float* x  = (const float*)d_in[0];
  const int*  tok = (const int*)d_in[1];
  const float* wq = (const float*)d_in[2];
  const float* wk = (const float*)d_in[3];
  const float* wv = (const float*)d_in[4];
  const float* wo = (const float*)d_in[5];
  float* out = (float*)d_out;
  char* ws = (char*)d_ws;
  // ws layout: Xb 16MB (reused as Ctx) | WT 8MB | QKV 48MB (Q^T|K|VT)
  // RoPE table (512KB) lives in d_out's head: free scratch until k_gemm<1>
  // fully overwrites d_out at the end.
  if (ws_size < (size_t)75497472) return;
  h16* Xb  = (h16*)ws;
  h16* WT  = (h16*)(ws + (16u<<20));
  h16* QKV = (h16*)(ws + (24u<<20));
  float2* tab = (float2*)d_out;

  k_cvt_x<<<dim3(2048), dim3(256), 0, stream>>>(x, Xb);
  k_tab<<<dim3(256), dim3(256), 0, stream>>>(tok, tab);
  k_cvt_w<<<dim3(32,32,4), dim3(256), 0, stream>>>(wq, wk, wv, wo, WT);
  k_gemm<0><<<dim3(1536), dim3(256), 0, stream>>>(Xb, WT, (void*)QKV, tab);
  k_attn<<<dim3(512), dim3(256), 0, stream>>>(QKV,
                                              QKV + (size_t)64*SB*HDim,
                                              QKV + (size_t)128*SB*HDim,
                                              Xb);
  k_gemm<1><<<dim3(512), dim3(256), 0, stream>>>(Xb, WT + (size_t)3*DM*DM, (void*)out, nullptr);
}

// Round 15
// 171.875 us; speedup vs baseline: 1.2384x; 1.2384x over previous
//
#include <hip/hip_runtime.h>

// Problem constants (B=4, S=2048, D=1024, H=16, HD=64, theta=10000)
#define SB 2048
#define DM 1024
#define NH 16
#define HDim 64
#define NB 4
#define MROWS (NB*SB)   // 8192

typedef _Float16 h16;
typedef __attribute__((ext_vector_type(8))) _Float16 h16x8;
typedef __attribute__((ext_vector_type(4))) _Float16 h16x4;
typedef __attribute__((ext_vector_type(2))) _Float16 h16x2;
typedef __attribute__((ext_vector_type(2))) __fp16 fp16x2;
typedef __attribute__((ext_vector_type(4))) float f32x4;

typedef const __attribute__((address_space(1))) void* as1cp;
typedef __attribute__((address_space(3))) void* as3p;

__device__ __forceinline__ void gload16(const void* g, void* l){
  __builtin_amdgcn_global_load_lds((as1cp)g, (as3p)l, 16, 0, 0);
}
__device__ __forceinline__ int swz64(int a){ return a ^ (((a>>7)&3)<<4); }
__device__ __forceinline__ int swz128(int a){ return a ^ (((a>>7)&7)<<4); }
// V k-permutation (pos->k) inverse, used when writing VT (see round-1 notes)
__device__ __forceinline__ int invp3(int k){ return (k&32) | ((k&16)>>2) | ((k&12)<<1) | (k&3); }
__device__ __forceinline__ h16x2 pkrtz(float a, float b){
  fp16x2 r = __builtin_amdgcn_cvt_pkrtz(a,b);
  return __builtin_bit_cast(h16x2, r);
}

#define C1 0.18033688f   // 0.125 * log2(e); folded into wq at cvt_w

// ------- merged prep: [0,2048) cvt_x | [2048,6144) cvt_w(+C1 on wq) | [6144,6400) RoPE tab -------
__global__ void k_prep(const float* __restrict__ x, h16* __restrict__ xb,
                       const float* __restrict__ wq, const float* __restrict__ wk,
                       const float* __restrict__ wv, const float* __restrict__ wo,
                       h16* __restrict__ WT,
                       const int* __restrict__ tok, float2* __restrict__ tab){
  __shared__ h16 tile[32][33];
  const int blk = blockIdx.x;
  if (blk < 2048){
    const int n4 = MROWS*DM/4;
    for (int i = blk*blockDim.x + threadIdx.x; i < n4; i += 2048*blockDim.x){
      float4 v = ((const float4*)x)[i];
      h16x4 h; h[0]=(h16)v.x; h[1]=(h16)v.y; h[2]=(h16)v.z; h[3]=(h16)v.w;
      ((h16x4*)xb)[i] = h;
    }
  } else if (blk < 6144){
    const int local = blk - 2048;
    const int z = local >> 10, rem = local & 1023;
    const float* W = (z==0)?wq:(z==1)?wk:(z==2)?wv:wo;
    const float sc = (z==0) ? C1 : 1.0f;
    int tx = threadIdx.x & 31, ty = threadIdx.x >> 5;
    int n0 = (rem & 31)*32, k0 = (rem >> 5)*32;
    #pragma unroll
    for (int j=0;j<4;++j)
      tile[ty*4+j][tx] = (h16)(W[(size_t)(k0+ty*4+j)*DM + n0 + tx] * sc);
    __syncthreads();
    #pragma unroll
    for (int j=0;j<4;++j)
      WT[((size_t)z*DM + n0 + ty*4 + j)*DM + k0 + tx] = tile[tx][ty*4+j];
  } else {
    int i = (blk - 6144)*blockDim.x + threadIdx.x;   // 65536 entries
    int pr = i & 31, s = i >> 5;
    float inv = exp2f(-0.41524101f * (float)pr);
    float ang = (float)tok[s] * inv;
    float sn, cs; __sincosf(ang, &sn, &cs);
    tab[i] = make_float2(cs, sn);
  }
}

// -------- MFMA GEMM, 128x128 tile, BK=32, 4 waves, 2-phase LDS dbuf (R8-proven) --------
// XCD m-stripe partition (R13): XCD x owns m-panels [8x,8x+8); A stripe L2-resident.
// MODE 0: C=[8192]x[3072]; Q RoPE'd -> TRANSPOSED [bh][hd][s] (packed h16x4);
//         K RoPE'd -> [bh][s][hd] scatter; V -> permuted VT [bh][hd][pos].
// MODE 1: C=[8192]x[1024] -> fp32 linear to d_out
template<int MODE>
__global__ __launch_bounds__(256) void k_gemm(const h16* __restrict__ A,
                                              const h16* __restrict__ Bw,
                                              void* __restrict__ outp,
                                              const float2* __restrict__ tab){
  __shared__ __align__(16) char lds[32768];    // 2 x (As 8KB | Bs 8KB)
  const int t = threadIdx.x, lane = t & 63, wave = t >> 6;
  // XCD m-stripe block map (grid: MODE0=1536, MODE1=512; both %8==0)
  const int lin = blockIdx.x;
  const int x = lin & 7, local = lin >> 3;
  int m0p, n0p;
  if (MODE==0){ n0p = local % 24; m0p = local / 24; }
  else        { n0p = local & 7;  m0p = local >> 3; }
  const int m0 = (x*8 + m0p)*128, n0 = n0p*128;
  const int wm = (wave >> 1)*64, wn = (wave & 1)*64;
  // thread-constant staging offsets
  const int o0 = t*16, o1 = o0 + 4096;
  const int q0_ = swz64(o0), q1_ = swz64(o1);
  const int r0 = q0_ >> 6, c0 = q0_ & 63, r1 = q1_ >> 6, c1 = q1_ & 63;
  f32x4 acc[4][4] = {};
  { // prologue: stage tile 0 into buf 0
    gload16((const char*)A  + (size_t)(m0+r0)*2048 + c0, lds + o0);
    gload16((const char*)A  + (size_t)(m0+r1)*2048 + c1, lds + o1);
    gload16((const char*)Bw + (size_t)(n0+r0)*2048 + c0, lds + 8192 + o0);
    gload16((const char*)Bw + (size_t)(n0+r1)*2048 + c1, lds + 8192 + o1);
  }
  int cur = 0;
  for (int k0 = 0; k0 < DM; k0 += 32){
    __syncthreads();                       // vmcnt(0): buf[cur] staged; prev reads done
    if (k0 + 32 < DM){                     // stage next tile into buf[cur^1]
      const char* Ak = (const char*)A  + (k0+32)*2;
      const char* Bk = (const char*)Bw + (k0+32)*2;
      char* As1 = lds + (cur^1)*16384;
      gload16(Ak + (size_t)(m0+r0)*2048 + c0, As1 + o0);
      gload16(Ak + (size_t)(m0+r1)*2048 + c1, As1 + o1);
      gload16(Bk + (size_t)(n0+r0)*2048 + c0, As1 + 8192 + o0);
      gload16(Bk + (size_t)(n0+r1)*2048 + c1, As1 + 8192 + o1);
    }
    const char* As = lds + cur*16384;
    const char* Bs = As + 8192;
    h16x8 af[4], bf[4];
    #pragma unroll
    for (int f=0; f<4; ++f){
      int ao = (wm + f*16 + (lane&15))*64 + 16*(lane>>4);
      af[f] = *(const h16x8*)(As + swz64(ao));
      int bo = (wn + f*16 + (lane&15))*64 + 16*(lane>>4);
      bf[f] = *(const h16x8*)(Bs + swz64(bo));
    }
    __builtin_amdgcn_s_setprio(1);
    #pragma unroll
    for (int fm=0; fm<4; ++fm)
      #pragma unroll
      for (int fn=0; fn<4; ++fn)
        acc[fm][fn] = __builtin_amdgcn_mfma_f32_16x16x32_f16(af[fm], bf[fn], acc[fm][fn], 0,0,0);
    __builtin_amdgcn_s_setprio(0);
    cur ^= 1;
  }
  // epilogue; D layout: col = lane&15, row = 4*(lane>>4)+r
  #pragma unroll
  for (int fm=0; fm<4; ++fm){
    int grow0 = m0 + wm + fm*16 + 4*(lane>>4);
    #pragma unroll
    for (int fn=0; fn<4; ++fn){
      int gcol = n0 + wn + fn*16 + (lane&15);
      if (MODE == 0){
        int mat = gcol >> 10;                 // wave-uniform per fn
        int hh = (gcol >> 6) & 15, d = gcol & 63;
        if (mat == 0){
          // Q: RoPE then TRANSPOSED store [bh][d][s], packed h16x4 (s-contiguous)
          const int pr = d >> 1;
          int s0 = grow0 & 2047, b2 = grow0 >> 11;
          int bh = b2*16 + hh;
          float rs4[4];
          #pragma unroll
          for (int r=0;r<4;++r){
            float2 t2 = tab[(s0+r)*32 + pr];
            float val = acc[fm][fn][r];
            float oth = __shfl_xor(val, 1);
            rs4[r] = fmaf(val, t2.x, (d & 1) ? oth*t2.y : -(oth*t2.y));
          }
          union { h16x4 v4; h16x2 h2[2]; } u;
          u.h2[0] = pkrtz(rs4[0], rs4[1]);
          u.h2[1] = pkrtz(rs4[2], rs4[3]);
          *(h16x4*)((h16*)outp + (size_t)bh*131072 + (size_t)d*2048 + s0) = u.v4;
        } else if (mat == 1){
          // K: RoPE then [64+bh][s][hd] scatter (attn stages K rows by s)
          const int pr = d >> 1;
          #pragma unroll
          for (int r=0;r<4;++r){
            int grow = grow0 + r;
            int s = grow & 2047, b2 = grow >> 11;
            float2 t2 = tab[s*32 + pr];
            float val = acc[fm][fn][r];
            float oth = __shfl_xor(val, 1);
            float res = fmaf(val, t2.x, (d & 1) ? oth*t2.y : -(oth*t2.y));
            ((h16*)outp)[((size_t)(64 + b2*16 + hh)*SB + s)*HDim + d] = (h16)res;
          }
        } else {
          // VT scatter: pos runs consecutively with r -> one h16x4 store
          int s0 = grow0 & 2047, b2 = grow0 >> 11;
          int bh = b2*16 + hh;
          int pos0 = (s0 & ~63) + invp3(s0 & 63);
          union { h16x4 v4; h16x2 h2[2]; } u;
          u.h2[0] = pkrtz(acc[fm][fn][0], acc[fm][fn][1]);
          u.h2[1] = pkrtz(acc[fm][fn][2], acc[fm][fn][3]);
          *(h16x4*)((h16*)outp + (size_t)(128 + bh)*131072 + (size_t)d*2048 + pos0) = u.v4;
        }
      } else {
        #pragma unroll
        for (int r=0;r<4;++r){
          int grow = grow0 + r;
          ((float*)outp)[(size_t)grow*DM + gcol] = acc[fm][fn][r];
        }
      }
    }
  }
}

// ------- causal flash attention: 8 waves x 16q, paired-static, KVBLK=128/barrier -------
// 512 blocks x 512 thr. Block = (bh, pair p): q-tiles J=15-p then J=p -> 17
// stage-steps/block (constant). Each step stages TWO 64-key sub-tiles (stored as
// independent 8KB sub-tiles; proven swz layout unchanged) -> barriers halved vs R13.
// LDS 64KB -> 2 blocks/CU (same co-residency as 32KB config). QK^T: mfma(K,Q) ->
// lane owns q-row. P = exp2(s) directly (Q pre-scaled by C1). Row-sum via
// mfma(ones,P). PV: mfma(VT,P), VT pre-permuted (invp3). Q gathered from
// transposed [bh][hd][s] layout once per segment.
__global__ __launch_bounds__(512, 4) void k_attn(const h16* __restrict__ Qh,
                                                 const h16* __restrict__ Kh,
                                                 const h16* __restrict__ VTh,
                                                 h16* __restrict__ Ctx){
  __shared__ __align__(16) char Kl[2][16384];  // 2 sub-tiles x [64 k][64 hd], swz128
  __shared__ __align__(16) char Vl[2][16384];  // 2 sub-tiles x [64 hd][64 pos], swz128
  const int t = threadIdx.x, lane = t & 63, wave = t >> 6;
  const int g = lane >> 4, l15 = lane & 15;
  // lane-constant LDS read bases (see R4 notes): addr = kb_hs + 2048*u
  const int msk = (l15 & 7) << 4;
  const int kb0 = ((l15 << 7) + (g << 4)) ^ msk;
  const int kb1 = kb0 ^ 64;
  // thread-constant staging offsets (512 threads cover one 8KB sub-tile at 16B each)
  const int o0 = t*16;
  const int lo0 = swz128(o0);
  const int vof0 = ((lo0 >> 7) << 12) + (lo0 & 127);
  h16x8 ones;
  #pragma unroll
  for (int i=0;i<8;++i) ones[i] = (h16)1.0f;

  // static XCD-clustered item map: bh's 8 pair-blocks share blockIdx%8 -> one XCD
  const int lin = blockIdx.x;
  const int sz = (lin & 7)*64 + (lin >> 3);
  const int bh = sz >> 3, pr = sz & 7;
  const char* Qb = (const char*)Qh + (size_t)bh*262144;   // [64 hd][2048 s]
  const char* Kb = (const char*)Kh + (size_t)bh*262144;   // [2048 s][64 hd]
  const char* Vb = (const char*)VTh + (size_t)bh*262144;  // [64 hd][2048 pos]
  const int b = bh >> 4, h = bh & 15;

  #pragma unroll
  for (int seg=0; seg<2; ++seg){
    const int J = seg ? pr : (15 - pr);    // heavy tile first
    const int qw = (J << 7) + wave*16;     // wave owns q in [qw, qw+16)
    // gather Q fragments from transposed layout: q row = qw+l15, hd = 8g+j (+32)
    union { h16x8 v; h16 e[8]; } uq0, uq1;
    const char* Qcol = Qb + (size_t)(qw + l15)*2;
    #pragma unroll
    for (int j=0;j<8;++j){
      uq0.e[j] = *(const h16*)(Qcol + (size_t)(8*g + j)*4096);
      uq1.e[j] = *(const h16*)(Qcol + (size_t)(32 + 8*g + j)*4096);
    }
    const h16x8 qf0 = uq0.v, qf1 = uq1.v;
    f32x4 acc[4] = {};
    float lrow = 0.f;
    const int nkt = J + 1;                 // 128-key steps
    const char* kS = Kb + lo0;
    const char* vS = Vb + vof0;
    __syncthreads();                       // prior seg's LDS reads done
    gload16(kS,        &Kl[0][o0]);
    gload16(kS + 8192, &Kl[0][8192 + o0]);
    gload16(vS,        &Vl[0][o0]);
    gload16(vS + 128,  &Vl[0][8192 + o0]);
    int buf = 0;
    for (int kt=0; kt<nkt; ++kt){
      __syncthreads();                     // drains vmcnt, publishes buf
      if (kt+1 < nkt){
        const size_t kB = (size_t)(kt+1)*16384, vB = (size_t)(kt+1)*256;
        gload16(kS + kB,        &Kl[buf^1][o0]);
        gload16(kS + kB + 8192, &Kl[buf^1][8192 + o0]);
        gload16(vS + vB,        &Vl[buf^1][o0]);
        gload16(vS + vB + 128,  &Vl[buf^1][8192 + o0]);
      }
      #pragma unroll
      for (int n=0; n<2; ++n){
        const int k0 = kt*128 + 64*n;
        if (k0 <= qw + 15){                // wave-uniform causal skip (per sub-tile)
          const char* Kt = &Kl[buf][n*8192];
          const char* Vt = &Vl[buf][n*8192];
          f32x4 sfr[4] = {};
          {
            h16x8 kf0[4];
            #pragma unroll
            for (int kf=0;kf<4;++kf) kf0[kf] = *(const h16x8*)(Kt + kb0 + 2048*kf);
            __builtin_amdgcn_s_setprio(1);
            #pragma unroll
            for (int kf=0;kf<4;++kf)
              sfr[kf] = __builtin_amdgcn_mfma_f32_16x16x32_f16(kf0[kf], qf0, sfr[kf], 0,0,0);
            __builtin_amdgcn_s_setprio(0);
            h16x8 kf1[4];
            #pragma unroll
            for (int kf=0;kf<4;++kf) kf1[kf] = *(const h16x8*)(Kt + kb1 + 2048*kf);
            __builtin_amdgcn_s_setprio(1);
            #pragma unroll
            for (int kf=0;kf<4;++kf)
              sfr[kf] = __builtin_amdgcn_mfma_f32_16x16x32_f16(kf1[kf], qf1, sfr[kf], 0,0,0);
            __builtin_amdgcn_s_setprio(0);
          }
          if (k0 + 63 > qw){               // diagonal sub-tile: causal mask
            const int qg = qw + l15;
            #pragma unroll
            for (int kf=0;kf<4;++kf){
              const int kb = k0 + 16*kf + 4*g;
              #pragma unroll
              for (int r=0;r<4;++r)
                if (kb + r > qg) sfr[kf][r] = -1e30f;
            }
          }
          float e[4][4];
          #pragma unroll
          for (int kf=0;kf<4;++kf)
            #pragma unroll
            for (int r=0;r<4;++r)
              e[kf][r] = exp2f(sfr[kf][r]);
          h16x8 pa[2];
          #pragma unroll
          for (int s=0;s<2;++s){
            union { h16x8 v8; h16x2 h2[4]; } u;
            u.h2[0] = pkrtz(e[2*s][0],   e[2*s][1]);
            u.h2[1] = pkrtz(e[2*s][2],   e[2*s][3]);
            u.h2[2] = pkrtz(e[2*s+1][0], e[2*s+1][1]);
            u.h2[3] = pkrtz(e[2*s+1][2], e[2*s+1][3]);
            pa[s] = u.v8;
          }
          f32x4 zs = {};
          zs = __builtin_amdgcn_mfma_f32_16x16x32_f16(ones, pa[0], zs, 0,0,0);
          zs = __builtin_amdgcn_mfma_f32_16x16x32_f16(ones, pa[1], zs, 0,0,0);
          #pragma unroll
          for (int s=0;s<2;++s){
            h16x8 vb2[4];
            const int base = s ? kb1 : kb0;
            #pragma unroll
            for (int v=0;v<4;++v) vb2[v] = *(const h16x8*)(Vt + base + 2048*v);
            __builtin_amdgcn_s_setprio(1);
            #pragma unroll
            for (int v=0;v<4;++v)
              acc[v] = __builtin_amdgcn_mfma_f32_16x16x32_f16(vb2[v], pa[s], acc[v], 0,0,0);
            __builtin_amdgcn_s_setprio(0);
          }
          lrow += zs[0];
        }
      }
      buf ^= 1;
    }
    // epilogue: lane owns row q = qw+l15; cols hd = 16v+4g+r -> packed 8B stores
    const float rinv = 1.0f / lrow;
    h16* basep = Ctx + ((size_t)(b*SB + qw + l15))*DM + h*64 + (g<<2);
    #pragma unroll
    for (int v=0;v<4;++v){
      union { h16x4 v4; h16x2 h2[2]; } u;
      u.h2[0] = pkrtz(acc[v][0]*rinv, acc[v][1]*rinv);
      u.h2[1] = pkrtz(acc[v][2]*rinv, acc[v][3]*rinv);
      *(h16x4*)(basep + 16*v) = u.v4;
    }
  }
}

extern "C" void kernel_launch(void* const* d_in, const int* in_sizes, int n_in,
                              void* d_out, int out_size, void* d_ws, size_t ws_size,
                              hipStream_t stream) {
  const float* x  = (const float*)d_in[0];
  const int*  tok = (const int*)d_in[1];
  const float* wq = (const float*)d_in[2];
  const float* wk = (const float*)d_in[3];
  const float* wv = (const float*)d_in[4];
  const float* wo = (const float*)d_in[5];
  float* out = (float*)d_out;
  char* ws = (char*)d_ws;
  // ws layout: Xb 16MB (reused as Ctx) | WT 8MB | QKV 48MB (Q^T|K|VT)
  // RoPE table (512KB) lives in d_out's head: free scratch until k_gemm<1>
  // fully overwrites d_out at the end.
  if (ws_size < (size_t)75497472) return;
  h16* Xb  = (h16*)ws;
  h16* WT  = (h16*)(ws + (16u<<20));
  h16* QKV = (h16*)(ws + (24u<<20));
  float2* tab = (float2*)d_out;

  k_prep<<<dim3(6400), dim3(256), 0, stream>>>(x, Xb, wq, wk, wv, wo, WT, tok, tab);
  k_gemm<0><<<dim3(1536), dim3(256), 0, stream>>>(Xb, WT, (void*)QKV, tab);
  k_attn<<<dim3(512), dim3(512), 0, stream>>>(QKV,
                                              QKV + (size_t)64*SB*HDim,
                                              QKV + (size_t)128*SB*HDim,
                                              Xb);
  k_gemm<1><<<dim3(512), dim3(256), 0, stream>>>(Xb, WT + (size_t)3*DM*DM, (void*)out, nullptr);
}

// Round 16
// 167.029 us; speedup vs baseline: 1.2744x; 1.0290x over previous
//
#include <hip/hip_runtime.h>

// Problem constants (B=4, S=2048, D=1024, H=16, HD=64, theta=10000)
#define SB 2048
#define DM 1024
#define NH 16
#define HDim 64
#define NB 4
#define MROWS (NB*SB)   // 8192

typedef _Float16 h16;
typedef __attribute__((ext_vector_type(8))) _Float16 h16x8;
typedef __attribute__((ext_vector_type(4))) _Float16 h16x4;
typedef __attribute__((ext_vector_type(2))) _Float16 h16x2;
typedef __attribute__((ext_vector_type(2))) __fp16 fp16x2;
typedef __attribute__((ext_vector_type(4))) float f32x4;

typedef const __attribute__((address_space(1))) void* as1cp;
typedef __attribute__((address_space(3))) void* as3p;

__device__ __forceinline__ void gload16(const void* g, void* l){
  __builtin_amdgcn_global_load_lds((as1cp)g, (as3p)l, 16, 0, 0);
}
__device__ __forceinline__ int swz128(int a){ return a ^ (((a>>7)&7)<<4); }
// V k-permutation (pos->k) inverse, used when writing VT (see round-1 notes)
__device__ __forceinline__ int invp3(int k){ return (k&32) | ((k&16)>>2) | ((k&12)<<1) | (k&3); }
__device__ __forceinline__ h16x2 pkrtz(float a, float b){
  fp16x2 r = __builtin_amdgcn_cvt_pkrtz(a,b);
  return __builtin_bit_cast(h16x2, r);
}

#define C1 0.18033688f   // 0.125 * log2(e); folded into wq at cvt_w

// ------- merged prep: [0,2048) cvt_x | [2048,6144) cvt_w(+C1 on wq) | [6144,6400) RoPE tab -------
__global__ void k_prep(const float* __restrict__ x, h16* __restrict__ xb,
                       const float* __restrict__ wq, const float* __restrict__ wk,
                       const float* __restrict__ wv, const float* __restrict__ wo,
                       h16* __restrict__ WT,
                       const int* __restrict__ tok, float2* __restrict__ tab){
  __shared__ h16 tile[32][33];
  const int blk = blockIdx.x;
  if (blk < 2048){
    const int n4 = MROWS*DM/4;
    for (int i = blk*blockDim.x + threadIdx.x; i < n4; i += 2048*blockDim.x){
      float4 v = ((const float4*)x)[i];
      h16x4 h; h[0]=(h16)v.x; h[1]=(h16)v.y; h[2]=(h16)v.z; h[3]=(h16)v.w;
      ((h16x4*)xb)[i] = h;
    }
  } else if (blk < 6144){
    const int local = blk - 2048;
    const int z = local >> 10, rem = local & 1023;
    const float* W = (z==0)?wq:(z==1)?wk:(z==2)?wv:wo;
    const float sc = (z==0) ? C1 : 1.0f;
    int tx = threadIdx.x & 31, ty = threadIdx.x >> 5;
    int n0 = (rem & 31)*32, k0 = (rem >> 5)*32;
    #pragma unroll
    for (int j=0;j<4;++j)
      tile[ty*4+j][tx] = (h16)(W[(size_t)(k0+ty*4+j)*DM + n0 + tx] * sc);
    __syncthreads();
    #pragma unroll
    for (int j=0;j<4;++j)
      WT[((size_t)z*DM + n0 + ty*4 + j)*DM + k0 + tx] = tile[tx][ty*4+j];
  } else {
    int i = (blk - 6144)*blockDim.x + threadIdx.x;   // 65536 entries
    int pr = i & 31, s = i >> 5;
    float inv = exp2f(-0.41524101f * (float)pr);
    float ang = (float)tok[s] * inv;
    float sn, cs; __sincosf(ang, &sn, &cs);
    tab[i] = make_float2(cs, sn);
  }
}

// -------- MFMA GEMM, 128x128 tile, BK=64/barrier, 4 waves, 2-phase LDS dbuf --------
// Same proven 2-phase sync as R8-R15; K-depth per staged step doubled (32 MFMA
// between barriers, attn-R15's lever). Panels [128 rows][64 k], 128B rows,
// swz128 XOR layout (attn-proven, 0 bank conflicts). LDS 64KB -> 2 blocks/CU
// (= current measured residency). XCD m-stripe partition (R13).
// MODE 0: C=[8192]x[3072]; Q RoPE'd -> TRANSPOSED [bh][hd][s]; K RoPE'd ->
//         [bh][s][hd]; V -> permuted VT [bh][hd][pos].
// MODE 1: C=[8192]x[1024] -> fp32 linear to d_out
template<int MODE>
__global__ __launch_bounds__(256) void k_gemm(const h16* __restrict__ A,
                                              const h16* __restrict__ Bw,
                                              void* __restrict__ outp,
                                              const float2* __restrict__ tab){
  __shared__ __align__(16) char lds[65536];    // 2 x (As 16KB | Bs 16KB)
  const int t = threadIdx.x, lane = t & 63, wave = t >> 6;
  const int g = lane >> 4, l15 = lane & 15;
  // XCD m-stripe block map (grid: MODE0=1536, MODE1=512; both %8==0)
  const int lin = blockIdx.x;
  const int x = lin & 7, local = lin >> 3;
  int m0p, n0p;
  if (MODE==0){ n0p = local % 24; m0p = local / 24; }
  else        { n0p = local & 7;  m0p = local >> 3; }
  const int m0 = (x*8 + m0p)*128, n0 = n0p*128;
  const int wm = (wave >> 1)*64, wn = (wave & 1)*64;
  // lane-constant LDS read bases: addr = base ^ (ks<<6) + f*2048 (attn-proven)
  const int msk = (l15 & 7) << 4;
  const int kbA = (((wm + l15) << 7) + (g << 4)) ^ msk;
  const int kbB = (((wn + l15) << 7) + (g << 4)) ^ msk;
  // thread-constant staging sources (pre-swizzled): 4 issues x 4KB per operand
  const char* Asrc[4]; const char* Bsrc[4]; int od[4];
  #pragma unroll
  for (int i=0;i<4;++i){
    int o = t*16 + i*4096; od[i] = o;
    int lo = swz128(o);
    int row = lo >> 7, kb = lo & 127;
    Asrc[i] = (const char*)A  + (size_t)(m0+row)*2048 + kb;
    Bsrc[i] = (const char*)Bw + (size_t)(n0+row)*2048 + kb;
  }
  auto STAGE = [&](int s, char* d){
    const int kk = s*128;                  // 64 k = 128 bytes along K
    #pragma unroll
    for (int i=0;i<4;++i) gload16(Asrc[i] + kk, d + od[i]);
    #pragma unroll
    for (int i=0;i<4;++i) gload16(Bsrc[i] + kk, d + 16384 + od[i]);
  };
  f32x4 acc[4][4] = {};
  STAGE(0, lds);                           // prologue: step 0 -> buf 0
  int cur = 0;
  for (int s = 0; s < 16; ++s){
    __syncthreads();                       // vmcnt(0): buf[cur] staged; prev reads done
    if (s + 1 < 16) STAGE(s+1, lds + (cur^1)*32768);
    const char* As = lds + cur*32768;
    const char* Bs = As + 16384;
    #pragma unroll
    for (int ks=0; ks<2; ++ks){
      h16x8 af[4], bf[4];
      #pragma unroll
      for (int f=0; f<4; ++f){
        af[f] = *(const h16x8*)(As + (kbA ^ (ks<<6)) + f*2048);
        bf[f] = *(const h16x8*)(Bs + (kbB ^ (ks<<6)) + f*2048);
      }
      __builtin_amdgcn_s_setprio(1);
      #pragma unroll
      for (int fm=0; fm<4; ++fm)
        #pragma unroll
        for (int fn=0; fn<4; ++fn)
          acc[fm][fn] = __builtin_amdgcn_mfma_f32_16x16x32_f16(af[fm], bf[fn], acc[fm][fn], 0,0,0);
      __builtin_amdgcn_s_setprio(0);
    }
    cur ^= 1;
  }
  // epilogue; D layout: col = lane&15, row = 4*(lane>>4)+r
  #pragma unroll
  for (int fm=0; fm<4; ++fm){
    int grow0 = m0 + wm + fm*16 + 4*g;
    #pragma unroll
    for (int fn=0; fn<4; ++fn){
      int gcol = n0 + wn + fn*16 + l15;
      if (MODE == 0){
        int mat = gcol >> 10;                 // wave-uniform per fn
        int hh = (gcol >> 6) & 15, d = gcol & 63;
        if (mat == 0){
          // Q: RoPE then TRANSPOSED store [bh][d][s], packed h16x4 (s-contiguous)
          const int pr = d >> 1;
          int s0 = grow0 & 2047, b2 = grow0 >> 11;
          int bh = b2*16 + hh;
          float rs4[4];
          #pragma unroll
          for (int r=0;r<4;++r){
            float2 t2 = tab[(s0+r)*32 + pr];
            float val = acc[fm][fn][r];
            float oth = __shfl_xor(val, 1);
            rs4[r] = fmaf(val, t2.x, (d & 1) ? oth*t2.y : -(oth*t2.y));
          }
          union { h16x4 v4; h16x2 h2[2]; } u;
          u.h2[0] = pkrtz(rs4[0], rs4[1]);
          u.h2[1] = pkrtz(rs4[2], rs4[3]);
          *(h16x4*)((h16*)outp + (size_t)bh*131072 + (size_t)d*2048 + s0) = u.v4;
        } else if (mat == 1){
          // K: RoPE then [64+bh][s][hd] scatter (attn stages K rows by s)
          const int pr = d >> 1;
          #pragma unroll
          for (int r=0;r<4;++r){
            int grow = grow0 + r;
            int s = grow & 2047, b2 = grow >> 11;
            float2 t2 = tab[s*32 + pr];
            float val = acc[fm][fn][r];
            float oth = __shfl_xor(val, 1);
            float res = fmaf(val, t2.x, (d & 1) ? oth*t2.y : -(oth*t2.y));
            ((h16*)outp)[((size_t)(64 + b2*16 + hh)*SB + s)*HDim + d] = (h16)res;
          }
        } else {
          // VT scatter: pos runs consecutively with r -> one h16x4 store
          int s0 = grow0 & 2047, b2 = grow0 >> 11;
          int bh = b2*16 + hh;
          int pos0 = (s0 & ~63) + invp3(s0 & 63);
          union { h16x4 v4; h16x2 h2[2]; } u;
          u.h2[0] = pkrtz(acc[fm][fn][0], acc[fm][fn][1]);
          u.h2[1] = pkrtz(acc[fm][fn][2], acc[fm][fn][3]);
          *(h16x4*)((h16*)outp + (size_t)(128 + bh)*131072 + (size_t)d*2048 + pos0) = u.v4;
        }
      } else {
        #pragma unroll
        for (int r=0;r<4;++r){
          int grow = grow0 + r;
          ((float*)outp)[(size_t)grow*DM + gcol] = acc[fm][fn][r];
        }
      }
    }
  }
}

// ------- causal flash attention: 8 waves x 16q, paired-static, KVBLK=128/barrier (R15) -------
// 512 blocks x 512 thr. Block = (bh, pair p): q-tiles J=15-p then J=p -> 17
// stage-steps/block (constant). Each step stages TWO 64-key sub-tiles (stored as
// independent 8KB sub-tiles). LDS 64KB -> 2 blocks/CU. QK^T: mfma(K,Q) -> lane
// owns q-row. P = exp2(s) directly (Q pre-scaled by C1). Row-sum via mfma(ones,P).
// PV: mfma(VT,P), VT pre-permuted (invp3). Q gathered from transposed [bh][hd][s].
__global__ __launch_bounds__(512, 4) void k_attn(const h16* __restrict__ Qh,
                                                 const h16* __restrict__ Kh,
                                                 const h16* __restrict__ VTh,
                                                 h16* __restrict__ Ctx){
  __shared__ __align__(16) char Kl[2][16384];  // 2 sub-tiles x [64 k][64 hd], swz128
  __shared__ __align__(16) char Vl[2][16384];  // 2 sub-tiles x [64 hd][64 pos], swz128
  const int t = threadIdx.x, lane = t & 63, wave = t >> 6;
  const int g = lane >> 4, l15 = lane & 15;
  // lane-constant LDS read bases (see R4 notes): addr = kb_hs + 2048*u
  const int msk = (l15 & 7) << 4;
  const int kb0 = ((l15 << 7) + (g << 4)) ^ msk;
  const int kb1 = kb0 ^ 64;
  // thread-constant staging offsets (512 threads cover one 8KB sub-tile at 16B each)
  const int o0 = t*16;
  const int lo0 = swz128(o0);
  const int vof0 = ((lo0 >> 7) << 12) + (lo0 & 127);
  h16x8 ones;
  #pragma unroll
  for (int i=0;i<8;++i) ones[i] = (h16)1.0f;

  // static XCD-clustered item map: bh's 8 pair-blocks share blockIdx%8 -> one XCD
  const int lin = blockIdx.x;
  const int sz = (lin & 7)*64 + (lin >> 3);
  const int bh = sz >> 3, pr = sz & 7;
  const char* Qb = (const char*)Qh + (size_t)bh*262144;   // [64 hd][2048 s]
  const char* Kb = (const char*)Kh + (size_t)bh*262144;   // [2048 s][64 hd]
  const char* Vb = (const char*)VTh + (size_t)bh*262144;  // [64 hd][2048 pos]
  const int b = bh >> 4, h = bh & 15;

  #pragma unroll
  for (int seg=0; seg<2; ++seg){
    const int J = seg ? pr : (15 - pr);    // heavy tile first
    const int qw = (J << 7) + wave*16;     // wave owns q in [qw, qw+16)
    // gather Q fragments from transposed layout: q row = qw+l15, hd = 8g+j (+32)
    union { h16x8 v; h16 e[8]; } uq0, uq1;
    const char* Qcol = Qb + (size_t)(qw + l15)*2;
    #pragma unroll
    for (int j=0;j<8;++j){
      uq0.e[j] = *(const h16*)(Qcol + (size_t)(8*g + j)*4096);
      uq1.e[j] = *(const h16*)(Qcol + (size_t)(32 + 8*g + j)*4096);
    }
    const h16x8 qf0 = uq0.v, qf1 = uq1.v;
    f32x4 acc[4] = {};
    float lrow = 0.f;
    const int nkt = J + 1;                 // 128-key steps
    const char* kS = Kb + lo0;
    const char* vS = Vb + vof0;
    __syncthreads();                       // prior seg's LDS reads done
    gload16(kS,        &Kl[0][o0]);
    gload16(kS + 8192, &Kl[0][8192 + o0]);
    gload16(vS,        &Vl[0][o0]);
    gload16(vS + 128,  &Vl[0][8192 + o0]);
    int buf = 0;
    for (int kt=0; kt<nkt; ++kt){
      __syncthreads();                     // drains vmcnt, publishes buf
      if (kt+1 < nkt){
        const size_t kB = (size_t)(kt+1)*16384, vB = (size_t)(kt+1)*256;
        gload16(kS + kB,        &Kl[buf^1][o0]);
        gload16(kS + kB + 8192, &Kl[buf^1][8192 + o0]);
        gload16(vS + vB,        &Vl[buf^1][o0]);
        gload16(vS + vB + 128,  &Vl[buf^1][8192 + o0]);
      }
      #pragma unroll
      for (int n=0; n<2; ++n){
        const int k0 = kt*128 + 64*n;
        if (k0 <= qw + 15){                // wave-uniform causal skip (per sub-tile)
          const char* Kt = &Kl[buf][n*8192];
          const char* Vt = &Vl[buf][n*8192];
          f32x4 sfr[4] = {};
          {
            h16x8 kf0[4];
            #pragma unroll
            for (int kf=0;kf<4;++kf) kf0[kf] = *(const h16x8*)(Kt + kb0 + 2048*kf);
            __builtin_amdgcn_s_setprio(1);
            #pragma unroll
            for (int kf=0;kf<4;++kf)
              sfr[kf] = __builtin_amdgcn_mfma_f32_16x16x32_f16(kf0[kf], qf0, sfr[kf], 0,0,0);
            __builtin_amdgcn_s_setprio(0);
            h16x8 kf1[4];
            #pragma unroll
            for (int kf=0;kf<4;++kf) kf1[kf] = *(const h16x8*)(Kt + kb1 + 2048*kf);
            __builtin_amdgcn_s_setprio(1);
            #pragma unroll
            for (int kf=0;kf<4;++kf)
              sfr[kf] = __builtin_amdgcn_mfma_f32_16x16x32_f16(kf1[kf], qf1, sfr[kf], 0,0,0);
            __builtin_amdgcn_s_setprio(0);
          }
          if (k0 + 63 > qw){               // diagonal sub-tile: causal mask
            const int qg = qw + l15;
            #pragma unroll
            for (int kf=0;kf<4;++kf){
              const int kb = k0 + 16*kf + 4*g;
              #pragma unroll
              for (int r=0;r<4;++r)
                if (kb + r > qg) sfr[kf][r] = -1e30f;
            }
          }
          float e[4][4];
          #pragma unroll
          for (int kf=0;kf<4;++kf)
            #pragma unroll
            for (int r=0;r<4;++r)
              e[kf][r] = exp2f(sfr[kf][r]);
          h16x8 pa[2];
          #pragma unroll
          for (int s=0;s<2;++s){
            union { h16x8 v8; h16x2 h2[4]; } u;
            u.h2[0] = pkrtz(e[2*s][0],   e[2*s][1]);
            u.h2[1] = pkrtz(e[2*s][2],   e[2*s][3]);
            u.h2[2] = pkrtz(e[2*s+1][0], e[2*s+1][1]);
            u.h2[3] = pkrtz(e[2*s+1][2], e[2*s+1][3]);
            pa[s] = u.v8;
          }
          f32x4 zs = {};
          zs = __builtin_amdgcn_mfma_f32_16x16x32_f16(ones, pa[0], zs, 0,0,0);
          zs = __builtin_amdgcn_mfma_f32_16x16x32_f16(ones, pa[1], zs, 0,0,0);
          #pragma unroll
          for (int s=0;s<2;++s){
            h16x8 vb2[4];
            const int base = s ? kb1 : kb0;
            #pragma unroll
            for (int v=0;v<4;++v) vb2[v] = *(const h16x8*)(Vt + base + 2048*v);
            __builtin_amdgcn_s_setprio(1);
            #pragma unroll
            for (int v=0;v<4;++v)
              acc[v] = __builtin_amdgcn_mfma_f32_16x16x32_f16(vb2[v], pa[s], acc[v], 0,0,0);
            __builtin_amdgcn_s_setprio(0);
          }
          lrow += zs[0];
        }
      }
      buf ^= 1;
    }
    // epilogue: lane owns row q = qw+l15; cols hd = 16v+4g+r -> packed 8B stores
    const float rinv = 1.0f / lrow;
    h16* basep = Ctx + ((size_t)(b*SB + qw + l15))*DM + h*64 + (g<<2);
    #pragma unroll
    for (int v=0;v<4;++v){
      union { h16x4 v4; h16x2 h2[2]; } u;
      u.h2[0] = pkrtz(acc[v][0]*rinv, acc[v][1]*rinv);
      u.h2[1] = pkrtz(acc[v][2]*rinv, acc[v][3]*rinv);
      *(h16x4*)(basep + 16*v) = u.v4;
    }
  }
}

extern "C" void kernel_launch(void* const* d_in, const int* in_sizes, int n_in,
                              void* d_out, int out_size, void* d_ws, size_t ws_size,
                              hipStream_t stream) {
  const float* x  = (const float*)d_in[0];
  const int*  tok = (const int*)d_in[1];
  const float* wq = (const float*)d_in[2];
  const float* wk = (const float*)d_in[3];
  const float* wv = (const float*)d_in[4];
  const float* wo = (const float*)d_in[5];
  float* out = (float*)d_out;
  char* ws = (char*)d_ws;
  // ws layout: Xb 16MB (reused as Ctx) | WT 8MB | QKV 48MB (Q^T|K|VT)
  // RoPE table (512KB) lives in d_out's head: free scratch until k_gemm<1>
  // fully overwrites d_out at the end.
  if (ws_size < (size_t)75497472) return;
  h16* Xb  = (h16*)ws;
  h16* WT  = (h16*)(ws + (16u<<20));
  h16* QKV = (h16*)(ws + (24u<<20));
  float2* tab = (float2*)d_out;

  k_prep<<<dim3(6400), dim3(256), 0, stream>>>(x, Xb, wq, wk, wv, wo, WT, tok, tab);
  k_gemm<0><<<dim3(1536), dim3(256), 0, stream>>>(Xb, WT, (void*)QKV, tab);
  k_attn<<<dim3(512), dim3(512), 0, stream>>>(QKV,
                                              QKV + (size_t)64*SB*HDim,
                                              QKV + (size_t)128*SB*HDim,
                                              Xb);
  k_gemm<1><<<dim3(512), dim3(256), 0, stream>>>(Xb, WT + (size_t)3*DM*DM, (void*)out, nullptr);
}